// Round 1
// 368.311 us; speedup vs baseline: 1.0354x; 1.0354x over previous
//
#include <hip/hip_runtime.h>
#include <math.h>

#define NBINS 15
#define NCLS 100
#define ECE_EPS 1e-5f

#define ROWS_PER_TILE 128
#define ROW_BYTES (NCLS * 4)                       // 400
#define TILE_BYTES (ROWS_PER_TILE * ROW_BYTES)     // 51200
#define CHUNKS (TILE_BYTES / 1024)                 // 50 wave-chunks of 64 lanes x 16B

typedef const __attribute__((address_space(1))) unsigned int* gas_ptr;
typedef __attribute__((address_space(3))) unsigned int* las_ptr;

// Kernel A: argmax histogram.
// NOTE: predictions = max(log_softmax) < 0 strictly (sum of exps > 1 for these
// inputs by a huge margin), labels >= 0, so accuracies == 0 identically: the exp/log
// pass and the labels read contribute nothing to the output and are dropped.
// Output depends only on integer argmax counts -> bit-identical to previous kernel.
//
// Coalescing: 128-row tile staged to LDS with global_load_lds width=16.
// The DMA writes LDS at (wave-uniform base + lane*16), which matches our linear
// row-major layout exactly; global source is per-lane coalesced (1 KiB / wave / inst).
__global__ __launch_bounds__(256) void ece_hist(const float* __restrict__ logits,
                                                int* __restrict__ g_cnt,
                                                int n_rows) {
    __shared__ __align__(16) char tile[TILE_BYTES];
    __shared__ int s_cnt[NCLS];

    const int tid  = threadIdx.x;
    const int lane = tid & 63;
    const int wave = tid >> 6;

    if (tid < NCLS) s_cnt[tid] = 0;
    __syncthreads();

    const int n_tiles = n_rows / ROWS_PER_TILE;

    for (int t = blockIdx.x; t < n_tiles; t += gridDim.x) {
        const char* gt = (const char*)logits + (long)t * TILE_BYTES;

        // ---- stage 128 rows (51.2 KB) to LDS, fully coalesced, no VGPR round-trip ----
        for (int k = wave; k < CHUNKS; k += 4) {
            __builtin_amdgcn_global_load_lds(
                (gas_ptr)(const void*)(gt + k * 1024 + lane * 16),
                (las_ptr)(void*)(&tile[k * 1024]),
                16, 0, 0);
        }
        __syncthreads();   // compiler drains vmcnt(0) before s_barrier

        // ---- 2 threads per row: each scans 50 contiguous floats from LDS ----
        const int r = tid >> 1;          // 0..127
        const int h = tid & 1;           // half: cols [h*50, h*50+50)
        const float2* rowp = (const float2*)(tile + r * ROW_BYTES) + h * 25;

        float m = -INFINITY; int mi = 0;
        #pragma unroll
        for (int i = 0; i < 25; ++i) {
            const float2 v = rowp[i];
            const int c = h * 50 + 2 * i;
            if (v.x > m) { m = v.x; mi = c; }
            if (v.y > m) { m = v.y; mi = c + 1; }
        }

        // ordered combine across the pair (t, t^1): ties go to half 0 = lower col,
        // preserving jnp.argmax first-occurrence semantics.
        const float mo = __shfl_xor(m, 1);
        const int   io = __shfl_xor(mi, 1);
        float mA, mB; int iA, iB;
        if (h == 0) { mA = m;  iA = mi; mB = mo; iB = io; }
        else        { mA = mo; iA = io; mB = m;  iB = mi; }
        const int MI = (mB > mA) ? iB : iA;

        if (h == 0) atomicAdd(&s_cnt[MI], 1);
        __syncthreads();   // protect tile before next iteration's DMA overwrites it
    }

    // ---- tail rows (n_rows % 128), zero for N=524288 but kept for robustness ----
    const int rem_start = n_tiles * ROWS_PER_TILE;
    for (int row = rem_start + blockIdx.x * blockDim.x + tid; row < n_rows;
         row += gridDim.x * blockDim.x) {
        const float* p = logits + (long)row * NCLS;
        float m = -INFINITY; int mi = 0;
        for (int c = 0; c < NCLS; ++c) { const float v = p[c]; if (v > m) { m = v; mi = c; } }
        atomicAdd(&s_cnt[mi], 1);
    }
    __syncthreads();

    if (tid < NCLS) {
        const int c = s_cnt[tid];
        if (c) atomicAdd(&g_cnt[tid], c);
    }
}

// Kernel B: fold the 100-entry histogram into the 15-bin sums and the final scalar.
// coeff(c,b) = softmax_b( -(c - anchor_b)^2 / 0.01 ), identical math to reference.
// g_acc stays all-zero (accuracies == 0), kept so the math shape matches reference.
__global__ void ece_final(const int* __restrict__ g_cnt,
                          const float* __restrict__ g_acc,
                          float* __restrict__ out) {
    __shared__ float s_bins[3 * NBINS];   // [0..14]=sum_coeffs, [15..29]=conf*coeff, [30..44]=acc*coeff
    const int tid = threadIdx.x;
    if (tid < 3 * NBINS) s_bins[tid] = 0.0f;
    __syncthreads();

    if (tid < NCLS) {
        const float cnt  = (float)g_cnt[tid];
        const float accv = g_acc[tid];
        const float conf = (float)tid;
        float diff[NBINS];
        float dm = -INFINITY;
        #pragma unroll
        for (int b = 0; b < NBINS; ++b) {
            const float a = (float)(2 * b + 1) * (1.0f / 30.0f);
            const float d = conf - a;
            diff[b] = -(d * d) * 100.0f;
            dm = fmaxf(dm, diff[b]);
        }
        float es = 0.0f;
        float e[NBINS];
        #pragma unroll
        for (int b = 0; b < NBINS; ++b) { e[b] = __expf(diff[b] - dm); es += e[b]; }
        const float inv = 1.0f / es;
        #pragma unroll
        for (int b = 0; b < NBINS; ++b) {
            const float coeff = e[b] * inv;
            atomicAdd(&s_bins[b],             cnt * coeff);
            atomicAdd(&s_bins[NBINS + b],     conf * cnt * coeff);
            atomicAdd(&s_bins[2 * NBINS + b], accv * coeff);
        }
    }
    __syncthreads();

    if (tid == 0) {
        float total = 0.0f;
        #pragma unroll
        for (int b = 0; b < NBINS; ++b) total += fabsf(s_bins[b]);
        const float invw = 1.0f / fmaxf(total, ECE_EPS);
        float ece = 0.0f;
        #pragma unroll
        for (int b = 0; b < NBINS; ++b) {
            const float sc = s_bins[b];
            const float denom = fmaxf(sc, ECE_EPS);
            const float bc = s_bins[NBINS + b] / denom;
            const float ba = s_bins[2 * NBINS + b] / denom;
            const float d  = bc - ba;
            ece += d * d * (sc * invw);
        }
        out[0] = sqrtf(ece);
    }
}

extern "C" void kernel_launch(void* const* d_in, const int* in_sizes, int n_in,
                              void* d_out, int out_size, void* d_ws, size_t ws_size,
                              hipStream_t stream) {
    const float* logits = (const float*)d_in[0];
    int*   g_cnt = (int*)d_ws;
    float* g_acc = (float*)((char*)d_ws + NCLS * sizeof(int));
    float* outp  = (float*)d_out;
    const int n_rows = in_sizes[1];   // labels element count = N

    hipMemsetAsync(d_ws, 0, NCLS * (sizeof(int) + sizeof(float)), stream);
    // 1024 blocks x 256 threads; 4096 tiles of 128 rows -> 4 tiles/block.
    // LDS 51.6 KB/block -> 3 blocks/CU = 12 waves/CU, ample TLP for HBM streaming.
    ece_hist<<<1024, 256, 0, stream>>>(logits, g_cnt, n_rows);
    ece_final<<<1, 128, 0, stream>>>(g_cnt, g_acc, outp);
}